// Round 13
// baseline (161.045 us; speedup 1.0000x reference)
//
#include <hip/hip_runtime.h>
#include <hip/hip_bf16.h>
#include <math.h>

#define N_TOK 4096
#define DIM   1024

typedef __attribute__((ext_vector_type(8))) short s16x8;
typedef __attribute__((ext_vector_type(4))) float f32x4;
typedef __attribute__((ext_vector_type(4))) int   i32x4;

#define SM_SCALE 3990.0f     // M = exp(tanh(s)/32)-1, |M|<=0.03177 -> |q|<=126.7
#define SV_SCALE 18.0f       // v ~ N(0,1); 127/18 = 7.05 sigma clip
#define PV_DEQ   (1.0f / (SM_SCALE * SV_SCALE))

__device__ inline short to_bf16(float f) {
  union { float f; unsigned u; } v; v.f = f;
  unsigned r = v.u + 0x7FFFu + ((v.u >> 16) & 1u);   // RNE
  return (short)(r >> 16);
}

__device__ inline void gload16(const void* g, void* l) {
  __builtin_amdgcn_global_load_lds(
      (const __attribute__((address_space(1))) unsigned int*)g,
      (__attribute__((address_space(3))) unsigned int*)l, 16, 0, 0);
}

// ---------------- cast fp32 -> bf16 ----------------
__global__ void cast_bf16_kernel(const float* __restrict__ in, short* __restrict__ out, int n) {
  int i = (blockIdx.x * blockDim.x + threadIdx.x) * 4;
  if (i >= n) return;
  float4 v = *reinterpret_cast<const float4*>(in + i);
  short4 o;
  o.x = to_bf16(v.x); o.y = to_bf16(v.y); o.z = to_bf16(v.z); o.w = to_bf16(v.w);
  *reinterpret_cast<short4*>(out + i) = o;
}

// ------- transpose + cast (3 weights in one launch via blockIdx.z) -------
__global__ void transpose_cast3_kernel(const float* __restrict__ Wq, const float* __restrict__ Wk,
                                       const float* __restrict__ Wv, short* __restrict__ WqkT,
                                       short* __restrict__ WvT) {
  __shared__ float tile[32][33];
  const float* in  = (blockIdx.z == 0) ? Wq : (blockIdx.z == 1) ? Wk : Wv;
  short* out = (blockIdx.z == 0) ? WqkT : (blockIdx.z == 1) ? (WqkT + DIM * DIM) : WvT;
  int bx = blockIdx.x * 32, by = blockIdx.y * 32;
  int tx = threadIdx.x, ty = threadIdx.y;   // block (32,8)
  #pragma unroll
  for (int i = 0; i < 32; i += 8)
    tile[ty + i][tx] = in[(size_t)(by + ty + i) * DIM + (bx + tx)];
  __syncthreads();
  #pragma unroll
  for (int i = 0; i < 32; i += 8)
    out[(size_t)(bx + ty + i) * DIM + (by + tx)] = to_bf16(tile[tx][ty + i]);
}

__device__ inline float fast_tanh(float x) {
  float e = __expf(2.0f * x);
  return 1.0f - 2.0f / (e + 1.0f);
}

__device__ inline signed char q8(float x, float s) {
  int q = __float2int_rn(x * s);
  q = q > 127 ? 127 : (q < -127 ? -127 : q);
  return (signed char)q;
}

// ========== 128x256 NT GEMM (bf16), BK=64: 11.4 uB/FLOP staging (vs 15.6 at 128^2) ====
// 512 threads, 8 waves (2M x 4N), 48KB LDS single-buffer, 2 blocks/CU.
// Same chunk-XOR swizzle idiom as verified 128^2 kernel (rows congruent mod 8
// across 64-row staging groups, so source pre-swizzle is group-invariant).
// EPI 0: +bias[col] -> bf16 ; EPI 2: M = exp(tanh(.)/32)-1 -> int8 + rowsum
template<int EPI>
__global__ __launch_bounds__(512, 2)
void gemm_wide(const short* __restrict__ A, const short* __restrict__ B,
               int lda, int ldb, int ldc, int NT,
               const float* __restrict__ aux, short* __restrict__ Cb,
               signed char* __restrict__ C8, float* __restrict__ redsum)
{
  __shared__ short As[128 * 64];   // 16 KB
  __shared__ short Bs[256 * 64];   // 32 KB
  const int t    = threadIdx.x;
  const int lane = t & 63;
  const int w    = t >> 6;          // 8 waves: 2(M) x 4(N)
  const int wr   = w >> 2, wc = w & 3;
  const int l15  = lane & 15, l4 = lane >> 4;

  // bijective XCD swizzle (total % 8 == 0)
  const int nx = gridDim.x, ny = gridDim.y;
  int lin = (int)blockIdx.y * nx + blockIdx.x;
  const int tot = nx * ny;
  int swz = (lin & 7) * (tot >> 3) + (lin >> 3);
  const int bxx = swz % nx;
  const int byy = swz / nx;

  // staging: thread t covers A rows {t>>3, 64+(t>>3)}, B rows {j*64+(t>>3)};
  // all rows congruent mod 8 -> one source pre-swizzle
  const int srow = t >> 3;
  const int sch  = ((t & 7) ^ (srow & 7)) * 8;
  const short* gA = A + (size_t)(byy * 128 + srow) * lda + sch;
  const short* gB = B + (size_t)(bxx * 256 + srow) * ldb + sch;
  const size_t a64 = (size_t)64 * lda;
  const size_t b64 = (size_t)64 * ldb, b128 = (size_t)128 * ldb, b192 = (size_t)192 * ldb;
  short* ldsA = &As[t * 8];
  short* ldsB = &Bs[t * 8];

  // hoisted read bases
  const int x7 = l15 & 7;
  const int abase0 = (wr * 64 + l15) * 64 + (l4 ^ x7) * 8;
  const int abase1 = abase0 ^ 32;
  const int bbase0 = (wc * 64 + l15) * 64 + (l4 ^ x7) * 8;
  const int bbase1 = bbase0 ^ 32;

  f32x4 acc[4][4];
  #pragma unroll
  for (int m = 0; m < 4; ++m)
    #pragma unroll
    for (int n = 0; n < 4; ++n)
      acc[m][n] = f32x4{0.f, 0.f, 0.f, 0.f};

  for (int kt = 0; kt < NT; ++kt) {
    gload16(gA,       ldsA);
    gload16(gA + a64, ldsA + 4096);
    gload16(gB,        ldsB);
    gload16(gB + b64,  ldsB + 4096);
    gload16(gB + b128, ldsB + 8192);
    gload16(gB + b192, ldsB + 12288);
    gA += 64; gB += 64;
    __syncthreads();
    {
      s16x8 af[4], bf[4];
      #pragma unroll
      for (int m = 0; m < 4; ++m) af[m] = *(const s16x8*)&As[abase0 + m * 1024];
      #pragma unroll
      for (int n = 0; n < 4; ++n) bf[n] = *(const s16x8*)&Bs[bbase0 + n * 1024];
      #pragma unroll
      for (int m = 0; m < 4; ++m)
        #pragma unroll
        for (int n = 0; n < 4; ++n)
          acc[m][n] = __builtin_amdgcn_mfma_f32_16x16x32_bf16(af[m], bf[n], acc[m][n], 0, 0, 0);
    }
    {
      s16x8 af[4], bf[4];
      #pragma unroll
      for (int m = 0; m < 4; ++m) af[m] = *(const s16x8*)&As[abase1 + m * 1024];
      #pragma unroll
      for (int n = 0; n < 4; ++n) bf[n] = *(const s16x8*)&Bs[bbase1 + n * 1024];
      #pragma unroll
      for (int m = 0; m < 4; ++m)
        #pragma unroll
        for (int n = 0; n < 4; ++n)
          acc[m][n] = __builtin_amdgcn_mfma_f32_16x16x32_bf16(af[m], bf[n], acc[m][n], 0, 0, 0);
    }
    __syncthreads();
  }

  const int rbase = byy * 128 + wr * 64;
  const int cbase = bxx * 256 + wc * 64;

  #pragma unroll
  for (int m = 0; m < 4; ++m) {
    #pragma unroll
    for (int r = 0; r < 4; ++r) {
      const int grow = rbase + m * 16 + l4 * 4 + r;
      if (EPI == 0) {
        #pragma unroll
        for (int n = 0; n < 4; ++n) {
          const int gcol = cbase + n * 16 + l15;
          Cb[(size_t)grow * ldc + gcol] = to_bf16(acc[m][n][r] + aux[gcol]);
        }
      } else {  // EPI == 2
        float rs = 0.f;
        #pragma unroll
        for (int n = 0; n < 4; ++n) {
          float Mv = __expf(fast_tanh(acc[m][n][r]) * 0.03125f) - 1.0f;
          int q = __float2int_rn(Mv * SM_SCALE);
          q = q > 127 ? 127 : (q < -127 ? -127 : q);
          rs += (float)q;
          C8[(size_t)grow * ldc + (cbase + n * 16 + l15)] = (signed char)q;
        }
        rs += __shfl_xor(rs, 1);
        rs += __shfl_xor(rs, 2);
        rs += __shfl_xor(rs, 4);
        rs += __shfl_xor(rs, 8);
        if (l15 == 0) atomicAdd(&redsum[grow], rs);   // rowsum of M in SM units
      }
    }
  }
}

// ============== m97-structure 128x128 NT GEMM (bf16) — v-proj only ==============
// EPI 1: +bias[row] -> int8 (v^T, scale SV) + atomic colsum of v (f32)
template<int EPI>
__global__ __launch_bounds__(256, 4)
void gemm128(const short* __restrict__ A, const short* __restrict__ B,
             int lda, int ldb, int ldc, int NT,
             const float* __restrict__ aux, signed char* __restrict__ C8,
             float* __restrict__ redsum)
{
  __shared__ short As[128 * 64];
  __shared__ short Bs[128 * 64];
  const int t    = threadIdx.x;
  const int lane = t & 63;
  const int wid  = t >> 6;
  const int wr   = wid >> 1, wc = wid & 1;
  const int l15  = lane & 15, l4 = lane >> 4;

  const int nx = gridDim.x, ny = gridDim.y;
  int lin = (int)blockIdx.y * nx + blockIdx.x;
  const int tot = nx * ny;
  int swz = (lin & 7) * (tot >> 3) + (lin >> 3);
  const int bxx = swz % nx;
  const int byy = swz / nx;

  const int srow = t >> 3;
  const int sch  = ((t & 7) ^ (srow & 7)) * 8;
  const short* gA = A + (size_t)(byy * 128 + srow) * lda + sch;
  const short* gB = B + (size_t)(bxx * 128 + srow) * ldb + sch;
  const size_t ra1 = (size_t)32 * lda, ra2 = (size_t)64 * lda, ra3 = (size_t)96 * lda;
  const size_t rb1 = (size_t)32 * ldb, rb2 = (size_t)64 * ldb, rb3 = (size_t)96 * ldb;
  short* ldsA = &As[t * 8];
  short* ldsB = &Bs[t * 8];

  const int x7 = l15 & 7;
  const int abase0 = (wr * 64 + l15) * 64 + (l4 ^ x7) * 8;
  const int abase1 = abase0 ^ 32;
  const int bbase0 = (wc * 64 + l15) * 64 + (l4 ^ x7) * 8;
  const int bbase1 = bbase0 ^ 32;

  f32x4 acc[4][4];
  #pragma unroll
  for (int m = 0; m < 4; ++m)
    #pragma unroll
    for (int n = 0; n < 4; ++n)
      acc[m][n] = f32x4{0.f, 0.f, 0.f, 0.f};

  for (int kt = 0; kt < NT; ++kt) {
    gload16(gA,       ldsA);
    gload16(gA + ra1, ldsA + 2048);
    gload16(gA + ra2, ldsA + 4096);
    gload16(gA + ra3, ldsA + 6144);
    gload16(gB,       ldsB);
    gload16(gB + rb1, ldsB + 2048);
    gload16(gB + rb2, ldsB + 4096);
    gload16(gB + rb3, ldsB + 6144);
    gA += 64; gB += 64;
    __syncthreads();
    {
      s16x8 af[4], bf[4];
      #pragma unroll
      for (int m = 0; m < 4; ++m) af[m] = *(const s16x8*)&As[abase0 + m * 1024];
      #pragma unroll
      for (int n = 0; n < 4; ++n) bf[n] = *(const s16x8*)&Bs[bbase0 + n * 1024];
      #pragma unroll
      for (int m = 0; m < 4; ++m)
        #pragma unroll
        for (int n = 0; n < 4; ++n)
          acc[m][n] = __builtin_amdgcn_mfma_f32_16x16x32_bf16(af[m], bf[n], acc[m][n], 0, 0, 0);
    }
    {
      s16x8 af[4], bf[4];
      #pragma unroll
      for (int m = 0; m < 4; ++m) af[m] = *(const s16x8*)&As[abase1 + m * 1024];
      #pragma unroll
      for (int n = 0; n < 4; ++n) bf[n] = *(const s16x8*)&Bs[bbase1 + n * 1024];
      #pragma unroll
      for (int m = 0; m < 4; ++m)
        #pragma unroll
        for (int n = 0; n < 4; ++n)
          acc[m][n] = __builtin_amdgcn_mfma_f32_16x16x32_bf16(af[m], bf[n], acc[m][n], 0, 0, 0);
    }
    __syncthreads();
  }

  const int rbase = byy * 128 + wr * 64;
  const int cbase = bxx * 128 + wc * 64;

  #pragma unroll
  for (int m = 0; m < 4; ++m) {
    #pragma unroll
    for (int r = 0; r < 4; ++r) {
      const int grow = rbase + m * 16 + l4 * 4 + r;
      const float bias = aux[grow];
      float rs = 0.f;
      #pragma unroll
      for (int n = 0; n < 4; ++n) {
        float val = acc[m][n][r] + bias;
        rs += val;
        C8[(size_t)grow * ldc + (cbase + n * 16 + l15)] = q8(val, SV_SCALE);
      }
      rs += __shfl_xor(rs, 1);
      rs += __shfl_xor(rs, 2);
      rs += __shfl_xor(rs, 4);
      rs += __shfl_xor(rs, 8);
      if (l15 == 0) atomicAdd(&redsum[grow], rs);
    }
  }
}

// ========= int8 PV GEMM, de-split: S = M_i8 @ v_i8^T, K=4096 (32 tiles) =========
// grid (8, 32) = 256 blocks. Epilogue writes fp32 out directly:
// out = (colsumV[col] + S*PV_DEQ) / (4096 + rowsumM[row]/SM_SCALE)
__global__ __launch_bounds__(256, 4)
void gemm_pv_i8(const signed char* __restrict__ A, const signed char* __restrict__ B,
                const float* __restrict__ rowsumM, const float* __restrict__ colsumV,
                float* __restrict__ outF)
{
  __shared__ __align__(16) signed char As[128 * 128];
  __shared__ __align__(16) signed char Bs[128 * 128];
  const int t    = threadIdx.x;
  const int lane = t & 63;
  const int wid  = t >> 6;
  const int wr   = wid >> 1, wc = wid & 1;
  const int l15  = lane & 15, l4 = lane >> 4;

  const int nx = gridDim.x, ny = gridDim.y;          // (8, 32)
  int lin = (int)blockIdx.y * nx + blockIdx.x;
  const int tot = nx * ny;
  int swz = (lin & 7) * (tot >> 3) + (lin >> 3);
  const int bxx = swz % nx;
  const int byy = swz / nx;

  const int srow = t >> 3;
  const int sch  = ((t & 7) ^ (srow & 7)) * 16;      // bytes
  const signed char* gA = A + (size_t)(byy * 128 + srow) * 4096 + sch;
  const signed char* gB = B + (size_t)(bxx * 128 + srow) * 4096 + sch;
  const size_t r1 = (size_t)32 * 4096, r2 = (size_t)64 * 4096, r3 = (size_t)96 * 4096;
  signed char* ldsA = &As[t * 16];
  signed char* ldsB = &Bs[t * 16];

  const int x7 = l15 & 7;
  const int abase0 = (wr * 64 + l15) * 128 + (l4 ^ x7) * 16;
  const int abase1 = abase0 ^ 64;
  const int bbase0 = (wc * 64 + l15) * 128 + (l4 ^ x7) * 16;
  const int bbase1 = bbase0 ^ 64;

  i32x4 acc[4][4];
  #pragma unroll
  for (int m = 0; m < 4; ++m)
    #pragma unroll
    for (int n = 0; n < 4; ++n)
      acc[m][n] = i32x4{0, 0, 0, 0};

  for (int kt = 0; kt < 32; ++kt) {
    gload16(gA,      ldsA);
    gload16(gA + r1, ldsA + 4096);
    gload16(gA + r2, ldsA + 8192);
    gload16(gA + r3, ldsA + 12288);
    gload16(gB,      ldsB);
    gload16(gB + r1, ldsB + 4096);
    gload16(gB + r2, ldsB + 8192);
    gload16(gB + r3, ldsB + 12288);
    gA += 128; gB += 128;
    __syncthreads();
    {
      i32x4 af[4], bf[4];
      #pragma unroll
      for (int m = 0; m < 4; ++m) af[m] = *(const i32x4*)&As[abase0 + m * 2048];
      #pragma unroll
      for (int n = 0; n < 4; ++n) bf[n] = *(const i32x4*)&Bs[bbase0 + n * 2048];
      #pragma unroll
      for (int m = 0; m < 4; ++m)
        #pragma unroll
        for (int n = 0; n < 4; ++n)
          acc[m][n] = __builtin_amdgcn_mfma_i32_16x16x64_i8(af[m], bf[n], acc[m][n], 0, 0, 0);
    }
    {
      i32x4 af[4], bf[4];
      #pragma unroll
      for (int m = 0; m < 4; ++m) af[m] = *(const i32x4*)&As[abase1 + m * 2048];
      #pragma unroll
      for (int n = 0; n < 4; ++n) bf[n] = *(const i32x4*)&Bs[bbase1 + n * 2048];
      #pragma unroll
      for (int m = 0; m < 4; ++m)
        #pragma unroll
        for (int n = 0; n < 4; ++n)
          acc[m][n] = __builtin_amdgcn_mfma_i32_16x16x64_i8(af[m], bf[n], acc[m][n], 0, 0, 0);
    }
    __syncthreads();
  }

  const int rbase = byy * 128 + wr * 64;
  const int cbase = bxx * 128 + wc * 64;

  #pragma unroll
  for (int m = 0; m < 4; ++m)
    #pragma unroll
    for (int r = 0; r < 4; ++r) {
      const int grow = rbase + m * 16 + l4 * 4 + r;
      const float invl = 1.0f / (4096.0f + rowsumM[grow] * (1.0f / SM_SCALE));
      #pragma unroll
      for (int n = 0; n < 4; ++n) {
        const int gcol = cbase + n * 16 + l15;
        outF[(size_t)grow * DIM + gcol] =
            (colsumV[gcol] + (float)acc[m][n][r] * PV_DEQ) * invl;
      }
    }
}

extern "C" void kernel_launch(void* const* d_in, const int* in_sizes, int n_in,
                              void* d_out, int out_size, void* d_ws, size_t ws_size,
                              hipStream_t stream) {
  const float* x  = (const float*)d_in[0];
  const float* Wq = (const float*)d_in[1];
  const float* bq = (const float*)d_in[2];
  const float* Wk = (const float*)d_in[3];
  const float* bk = (const float*)d_in[4];
  const float* Wv = (const float*)d_in[5];
  const float* bv = (const float*)d_in[6];
  float* out = (float*)d_out;

  char* ws = (char*)d_ws;
  short* xb        = (short*)(ws);                   //  8 MB  x bf16 [4096][1024]
  short* qk        = (short*)(ws + (8ull  << 20));   // 16 MB  q|k bf16 [4096][2048]
  signed char* v8  = (signed char*)(ws + (24ull << 20)); // 4 MB v^T int8 [1024][4096]
  short* WqkT      = (short*)(ws + (28ull << 20));   //  4 MB  [2048][1024]
  short* WvT       = (short*)(ws + (32ull << 20));   //  2 MB
  float* bqk       = (float*)(ws + (34ull << 20));   //  8 KB
  float* rowsumM   = (float*)(ws + (35ull << 20));   // 16 KB
  float* colsumV   = rowsumM + N_TOK;                //  4 KB
  signed char* M8  = (signed char*)(ws + (36ull << 20)); // 16 MB M int8 [4096][4096]

  hipMemsetAsync(rowsumM, 0, (N_TOK + DIM) * sizeof(float), stream);

  hipMemcpyAsync(bqk,        bq, DIM * sizeof(float), hipMemcpyDeviceToDevice, stream);
  hipMemcpyAsync(bqk + DIM,  bk, DIM * sizeof(float), hipMemcpyDeviceToDevice, stream);

  cast_bf16_kernel<<<(N_TOK * DIM / 4 + 255) / 256, 256, 0, stream>>>(x, xb, N_TOK * DIM);
  transpose_cast3_kernel<<<dim3(DIM / 32, DIM / 32, 3), dim3(32, 8), 0, stream>>>(
      Wq, Wk, Wv, WqkT, WvT);

  // q|k projection: [4096][2048] = x @ [WqT;WkT]^T + bqk   (128x256 tiles: grid 8x32)
  gemm_wide<0><<<dim3(8, 32), dim3(512), 0, stream>>>(
      xb, WqkT, DIM, DIM, 2 * DIM, 16, bqk, qk, nullptr, nullptr);
  // v^T int8 + colsum(v): [1024][4096]   (grid 32x8 = 256)
  gemm128<1><<<dim3(32, 8), dim3(256), 0, stream>>>(
      WvT, xb, DIM, DIM, N_TOK, 16, bv, v8, colsumV);
  // M = exp(tanh(q k^T)/32)-1 -> int8 + rowsum   (128x256 tiles: grid 16x32 = 512)
  gemm_wide<2><<<dim3(16, 32), dim3(512), 0, stream>>>(
      qk, qk + DIM, 2 * DIM, 2 * DIM, N_TOK, 16, nullptr, nullptr, M8, rowsumM);
  // PV int8, no split-K, direct fp32 epilogue   (grid 8x32 = 256)
  gemm_pv_i8<<<dim3(8, 32), dim3(256), 0, stream>>>(M8, v8, rowsumM, colsumV, out);
}